// Round 1
// baseline (571.764 us; speedup 1.0000x reference)
//
#include <hip/hip_runtime.h>

#define NN 100000
#define FF 256
#define DD 128
#define HH 4
#define CC 32
#define EE 1000000

// ---------------- GEMM: h = x @ W_lin + b  (fp32, LDS-tiled) ----------------
__global__ __launch_bounds__(256) void gemm_h(const float* __restrict__ x,
                                              const float* __restrict__ Wl,
                                              const float* __restrict__ bl,
                                              float* __restrict__ h) {
    __shared__ float xs[32][33];
    __shared__ float4 ws4[32][32];  // [kk][c4] : 32 k x 128 cols
    int t = threadIdx.x;
    int row0 = blockIdx.x * 32;
    int tr = t >> 4;   // 0..15 -> rows tr*2, tr*2+1
    int tc = t & 15;   // col groups: cols tc*4..+3 and 64+tc*4..+3

    float4 a0a = {0,0,0,0}, a0b = {0,0,0,0}, a1a = {0,0,0,0}, a1b = {0,0,0,0};

    for (int k0 = 0; k0 < FF; k0 += 32) {
        // x tile: 32 rows x 32 k = 256 float4, one per thread
        {
            int r = t >> 3, kk4 = t & 7;
            float4 xv = ((const float4*)(x + (size_t)(row0 + r) * FF + k0))[kk4];
            xs[r][kk4 * 4 + 0] = xv.x; xs[r][kk4 * 4 + 1] = xv.y;
            xs[r][kk4 * 4 + 2] = xv.z; xs[r][kk4 * 4 + 3] = xv.w;
        }
        // W tile: 32 k x 128 cols = 1024 float4, 4 per thread
        for (int j = 0; j < 4; ++j) {
            int i = t + 256 * j;
            int kk = i >> 5, c4 = i & 31;
            ws4[kk][c4] = ((const float4*)(Wl + (size_t)(k0 + kk) * DD))[c4];
        }
        __syncthreads();
        #pragma unroll
        for (int kk = 0; kk < 32; ++kk) {
            float x0 = xs[tr * 2 + 0][kk];
            float x1 = xs[tr * 2 + 1][kk];
            float4 w0 = ws4[kk][tc];
            float4 w1 = ws4[kk][tc + 16];
            a0a.x += x0 * w0.x; a0a.y += x0 * w0.y; a0a.z += x0 * w0.z; a0a.w += x0 * w0.w;
            a0b.x += x0 * w1.x; a0b.y += x0 * w1.y; a0b.z += x0 * w1.z; a0b.w += x0 * w1.w;
            a1a.x += x1 * w0.x; a1a.y += x1 * w0.y; a1a.z += x1 * w0.z; a1a.w += x1 * w0.w;
            a1b.x += x1 * w1.x; a1b.y += x1 * w1.y; a1b.z += x1 * w1.z; a1b.w += x1 * w1.w;
        }
        __syncthreads();
    }
    float4 b0 = ((const float4*)bl)[tc];
    float4 b1 = ((const float4*)bl)[tc + 16];
    float4* h0 = (float4*)(h + (size_t)(row0 + tr * 2 + 0) * DD);
    float4* h1 = (float4*)(h + (size_t)(row0 + tr * 2 + 1) * DD);
    float4 o;
    o.x = a0a.x + b0.x; o.y = a0a.y + b0.y; o.z = a0a.z + b0.z; o.w = a0a.w + b0.w; h0[tc] = o;
    o.x = a0b.x + b1.x; o.y = a0b.y + b1.y; o.z = a0b.z + b1.z; o.w = a0b.w + b1.w; h0[tc + 16] = o;
    o.x = a1a.x + b0.x; o.y = a1a.y + b0.y; o.z = a1a.z + b0.z; o.w = a1a.w + b0.w; h1[tc] = o;
    o.x = a1b.x + b1.x; o.y = a1b.y + b1.y; o.z = a1b.z + b1.z; o.w = a1b.w + b1.w; h1[tc + 16] = o;
}

// ---------------- beta = softmax(x @ Wc^T + bc) ----------------
__global__ __launch_bounds__(256) void beta_kernel(const float* __restrict__ x,
                                                   const float* __restrict__ Wc,
                                                   const float* __restrict__ bc,
                                                   float* __restrict__ beta) {
    int wid = threadIdx.x >> 6, lane = threadIdx.x & 63;
    int n = blockIdx.x * 4 + wid;
    const float* xr = x + (size_t)n * FF;
    float s0 = 0.f, s1 = 0.f, s2 = 0.f;
    #pragma unroll
    for (int j = 0; j < FF; j += 64) {
        float xv = xr[j + lane];
        s0 += xv * Wc[j + lane];
        s1 += xv * Wc[FF + j + lane];
        s2 += xv * Wc[2 * FF + j + lane];
    }
    for (int off = 32; off; off >>= 1) {
        s0 += __shfl_xor(s0, off);
        s1 += __shfl_xor(s1, off);
        s2 += __shfl_xor(s2, off);
    }
    if (lane == 0) {
        s0 += bc[0]; s1 += bc[1]; s2 += bc[2];
        float mx = fmaxf(s0, fmaxf(s1, s2));
        float e0 = __expf(s0 - mx), e1 = __expf(s1 - mx), e2 = __expf(s2 - mx);
        float inv = 1.f / (e0 + e1 + e2);
        beta[n * 3 + 0] = e0 * inv;
        beta[n * 3 + 1] = e1 * inv;
        beta[n * 3 + 2] = e2 * inv;
    }
}

// ---------------- al/ar attention dots per node ----------------
__global__ __launch_bounds__(256) void alr_kernel(const float* __restrict__ h,
                                                  const float* __restrict__ attn_l,
                                                  const float* __restrict__ attn_r,
                                                  float* __restrict__ AL,
                                                  float* __restrict__ AR) {
    int wid = threadIdx.x >> 6, lane = threadIdx.x & 63;
    int n = blockIdx.x * 4 + wid;
    float2 hv = ((const float2*)h)[(size_t)n * 64 + lane];
    int hd = lane >> 4;
    int cg = lane & 15;
    #pragma unroll
    for (int m = 0; m < 2; ++m) {
        float2 wl = ((const float2*)attn_l)[m * 64 + hd * 16 + cg];
        float2 wr = ((const float2*)attn_r)[m * 64 + hd * 16 + cg];
        float sl = hv.x * wl.x + hv.y * wl.y;
        float sr = hv.x * wr.x + hv.y * wr.y;
        for (int off = 1; off < 16; off <<= 1) {
            sl += __shfl_xor(sl, off);
            sr += __shfl_xor(sr, off);
        }
        if (cg == 0) {
            AL[(size_t)(m * NN + n) * 4 + hd] = sl;
            AR[(size_t)(m * NN + n) * 4 + hd] = sr;
        }
    }
}

// ---------------- CSR build ----------------
__global__ void count_kernel(const int* __restrict__ ei0, const int* __restrict__ ei1,
                             int* __restrict__ deg) {
    int e = blockIdx.x * 256 + threadIdx.x;
    if (e < EE) {
        atomicAdd(&deg[ei0[e]], 1);
    } else if (e < 2 * EE) {
        atomicAdd(&deg[NN + ei1[e - EE]], 1);
    }
}

__global__ __launch_bounds__(256) void scan1(const int* __restrict__ deg, int* __restrict__ rp,
                                             int* __restrict__ bsum, int L) {
    __shared__ int sm[256];
    int t = threadIdx.x;
    int i = blockIdx.x * 256 + t;
    int v = (i < L) ? deg[i] : 0;
    sm[t] = v;
    __syncthreads();
    for (int off = 1; off < 256; off <<= 1) {
        int o = (t >= off) ? sm[t - off] : 0;
        __syncthreads();
        sm[t] += o;
        __syncthreads();
    }
    if (i < L) rp[i] = sm[t] - v;  // exclusive within block
    if (t == 255) bsum[blockIdx.x] = sm[255];
}

__global__ __launch_bounds__(256) void scan2(int* __restrict__ bsum, int nb) {
    __shared__ int sm[256];
    int t = threadIdx.x;
    int carry = 0;
    for (int base = 0; base < nb; base += 256) {
        int i = base + t;
        int v = (i < nb) ? bsum[i] : 0;
        __syncthreads();
        sm[t] = v;
        __syncthreads();
        for (int off = 1; off < 256; off <<= 1) {
            int o = (t >= off) ? sm[t - off] : 0;
            __syncthreads();
            sm[t] += o;
            __syncthreads();
        }
        int incl = sm[t];
        int tot = sm[255];
        if (i < nb) bsum[i] = carry + incl - v;  // exclusive
        carry += tot;
    }
}

__global__ void scan3(int* __restrict__ rp, const int* __restrict__ bsum, int L) {
    int i = blockIdx.x * 256 + threadIdx.x;
    if (i < L) rp[i] += bsum[blockIdx.x];
    if (i == 0) rp[L] = 2 * EE;
}

__global__ void scatter_kernel(const int* __restrict__ ei0, const int* __restrict__ ei1,
                               const int* __restrict__ rp, int* __restrict__ cursor,
                               int* __restrict__ srcs) {
    int e = blockIdx.x * 256 + threadIdx.x;
    int idx, src;
    if (e < EE) {
        idx = ei0[e];            // dst, relation 0
        src = ei0[EE + e];
    } else if (e < 2 * EE) {
        int e1 = e - EE;
        idx = NN + ei1[e1];      // dst, relation 1
        src = ei1[EE + e1];
    } else {
        return;
    }
    int pos = rp[idx] + atomicAdd(&cursor[idx], 1);
    srcs[pos] = src;
}

// ---------------- main: per-dst-node softmax-aggregate + combine ----------------
__global__ __launch_bounds__(256) void main_kernel(const float* __restrict__ h,
                                                   const float* __restrict__ AL,
                                                   const float* __restrict__ AR,
                                                   const float* __restrict__ beta,
                                                   const float* __restrict__ alpha_act,
                                                   const int* __restrict__ rp,
                                                   const int* __restrict__ srcs,
                                                   float* __restrict__ out) {
    int wid = threadIdx.x >> 6, lane = threadIdx.x & 63;
    int n = blockIdx.x * 4 + wid;
    const float2* h2 = (const float2*)h;
    float2 hv = h2[(size_t)n * 64 + lane];
    int hd = lane >> 4;
    float b0 = beta[n * 3 + 0], b1 = beta[n * 3 + 1], b2 = beta[n * 3 + 2];
    float ox = b2 * hv.x, oy = b2 * hv.y;
    float bm[2] = {b0, b1};
    #pragma unroll
    for (int m = 0; m < 2; ++m) {
        float alv = AL[(size_t)(m * NN + n) * 4 + hd];
        float am = alpha_act[m];
        int e0 = rp[m * NN + n];
        int e1 = rp[m * NN + n + 1];
        float denom = 0.f, ax = 0.f, ay = 0.f;
        for (int e = e0; e < e1; ++e) {
            int s = srcs[e];
            float arv = AR[(size_t)(m * NN + s) * 4 + hd];
            float ex = __expf((arv + alv) * am);
            denom += ex;
            float2 sv = h2[(size_t)s * 64 + lane];
            ax += ex * sv.x;
            ay += ex * sv.y;
        }
        float invd = (denom > 0.f) ? (1.f / denom) : 0.f;
        ox += bm[m] * ax * invd;
        oy += bm[m] * ay * invd;
    }
    float2 res;
    res.x = fmaxf(ox, 0.f);
    res.y = fmaxf(oy, 0.f);
    ((float2*)out)[(size_t)n * 64 + lane] = res;
}

// ---------------- launch ----------------
extern "C" void kernel_launch(void* const* d_in, const int* in_sizes, int n_in,
                              void* d_out, int out_size, void* d_ws, size_t ws_size,
                              hipStream_t stream) {
    const float* x        = (const float*)d_in[0];
    const int*   ei0      = (const int*)d_in[1];
    const int*   ei1      = (const int*)d_in[2];
    const float* W_lin    = (const float*)d_in[3];
    const float* b_lin    = (const float*)d_in[4];
    const float* attn_l   = (const float*)d_in[5];
    const float* attn_r   = (const float*)d_in[6];
    const float* alpha    = (const float*)d_in[7];
    const float* W_conv   = (const float*)d_in[8];
    const float* b_conv   = (const float*)d_in[9];
    float* out = (float*)d_out;

    char* ws = (char*)d_ws;
    size_t off = 0;
    float* h_ws   = (float*)(ws + off); off += (size_t)NN * DD * 4;        // 51.2 MB
    float* AL     = (float*)(ws + off); off += (size_t)2 * NN * 4 * 4;     // 3.2 MB
    float* AR     = (float*)(ws + off); off += (size_t)2 * NN * 4 * 4;     // 3.2 MB
    float* beta   = (float*)(ws + off); off += (size_t)NN * 3 * 4;         // 1.2 MB
    int*   deg    = (int*)(ws + off);   off += (size_t)2 * NN * 4;         // 0.8 MB
    int*   cursor = (int*)(ws + off);   off += (size_t)2 * NN * 4;         // 0.8 MB
    int*   rp     = (int*)(ws + off);   off += ((size_t)2 * NN + 4) * 4;   // 0.8 MB
    int*   bsum   = (int*)(ws + off);   off += 1024 * 4;
    int*   srcs   = (int*)(ws + off);   off += (size_t)2 * EE * 4;         // 8 MB

    // zero deg + cursor (contiguous)
    hipMemsetAsync(deg, 0, (size_t)4 * NN * 4, stream);

    gemm_h<<<NN / 32, 256, 0, stream>>>(x, W_lin, b_lin, h_ws);
    beta_kernel<<<NN / 4, 256, 0, stream>>>(x, W_conv, b_conv, beta);
    alr_kernel<<<NN / 4, 256, 0, stream>>>(h_ws, attn_l, attn_r, AL, AR);
    count_kernel<<<(2 * EE + 255) / 256, 256, 0, stream>>>(ei0, ei1, deg);
    int L = 2 * NN;
    int nb = (L + 255) / 256;
    scan1<<<nb, 256, 0, stream>>>(deg, rp, bsum, L);
    scan2<<<1, 256, 0, stream>>>(bsum, nb);
    scan3<<<nb, 256, 0, stream>>>(rp, bsum, L);
    scatter_kernel<<<(2 * EE + 255) / 256, 256, 0, stream>>>(ei0, ei1, rp, cursor, srcs);
    main_kernel<<<NN / 4, 256, 0, stream>>>(h_ws, AL, AR, beta, alpha, rp, srcs, out);
}

// Round 3
// 385.631 us; speedup vs baseline: 1.4827x; 1.4827x over previous
//
#include <hip/hip_runtime.h>
#include <hip/hip_bf16.h>

#define NN 100000
#define FF 256
#define DD 128
#define EE 1000000

typedef __attribute__((ext_vector_type(4))) float f32x4;
typedef __attribute__((ext_vector_type(8))) short bf16x8;

__device__ __forceinline__ ushort f2bf(float f) {
    __hip_bfloat16 h = __float2bfloat16(f);
    return *reinterpret_cast<ushort*>(&h);
}
__device__ __forceinline__ float bf2f(ushort u) {
    return __uint_as_float(((uint)u) << 16);
}

// ---------------- pack W_lin (fp32 [256][128]) -> Wt (bf16 [128][256]) ----------------
__global__ void pack_w(const float* __restrict__ Wl, ushort* __restrict__ Wt) {
    int id = blockIdx.x * 256 + threadIdx.x;  // 32768 total
    int k = id >> 7, n = id & 127;
    Wt[n * FF + k] = f2bf(Wl[id]);
}

// ---------------- fused: h = x@W+b (bf16 MFMA), beta = softmax(x@Wc^T+bc) ----------------
__global__ __launch_bounds__(256) void fused_h(const float* __restrict__ x,
                                               const ushort* __restrict__ Wt,
                                               const float* __restrict__ bl,
                                               const float* __restrict__ Wc,
                                               const float* __restrict__ bc,
                                               ushort* __restrict__ hb,
                                               float* __restrict__ beta) {
    __shared__ ushort xs[64][72];    // 64 rows x BK=64 bf16, pad 8
    __shared__ ushort wsT[128][72];  // 128 cols x BK=64 bf16 (W transposed), pad 8
    __shared__ ushort hs[64][136];   // epilogue staging: 64 rows x 128, pad 8
    __shared__ float wcs[768];       // W_conv 3x256

    int t = threadIdx.x;
    int wv = t >> 6, lane = t & 63;
    int row0 = blockIdx.x * 64;
    int br = t >> 2, bq = t & 3;     // staging/beta: row br, k-quarter bq
    bool rowok = (row0 + br) < NN;

    if (t < 192) ((float4*)wcs)[t] = ((const float4*)Wc)[t];
    __syncthreads();

    f32x4 acc[8];
    #pragma unroll
    for (int i = 0; i < 8; ++i) acc[i] = (f32x4){0.f, 0.f, 0.f, 0.f};

    float bs0 = 0.f, bs1 = 0.f, bs2 = 0.f;

    for (int k0 = 0; k0 < FF; k0 += 64) {
        // stage x tile (fp32 -> bf16), accumulate beta partials in fp32
        if (rowok) {
            const float4* xp = (const float4*)(x + (size_t)(row0 + br) * FF + k0 + bq * 16);
            #pragma unroll
            for (int j = 0; j < 4; ++j) {
                float4 v = xp[j];
                int kk = bq * 16 + j * 4;
                const float* w0 = wcs + k0 + kk;
                bs0 += v.x * w0[0] + v.y * w0[1] + v.z * w0[2] + v.w * w0[3];
                const float* w1 = wcs + 256 + k0 + kk;
                bs1 += v.x * w1[0] + v.y * w1[1] + v.z * w1[2] + v.w * w1[3];
                const float* w2 = wcs + 512 + k0 + kk;
                bs2 += v.x * w2[0] + v.y * w2[1] + v.z * w2[2] + v.w * w2[3];
                ushort4 p;
                p.x = f2bf(v.x); p.y = f2bf(v.y); p.z = f2bf(v.z); p.w = f2bf(v.w);
                *(ushort4*)&xs[br][kk] = p;
            }
        } else {
            ushort4 z = {0, 0, 0, 0};
            #pragma unroll
            for (int j = 0; j < 4; ++j) *(ushort4*)&xs[br][bq * 16 + j * 4] = z;
        }
        // stage Wt tile: 128 cols x 64 k (bf16), 1024 uint4 segments of 8
        #pragma unroll
        for (int j = 0; j < 4; ++j) {
            int c = t + 256 * j;
            int rw = c >> 3, seg = c & 7;   // 128 rows x 8 segs
            uint4 v = *(const uint4*)(Wt + rw * FF + k0 + seg * 8);
            *(uint4*)&wsT[rw][seg * 8] = v;
        }
        __syncthreads();
        #pragma unroll
        for (int ks = 0; ks < 2; ++ks) {
            bf16x8 af = *(const bf16x8*)&xs[wv * 16 + (lane & 15)][ks * 32 + (lane >> 4) * 8];
            #pragma unroll
            for (int nt = 0; nt < 8; ++nt) {
                bf16x8 bv = *(const bf16x8*)&wsT[nt * 16 + (lane & 15)][ks * 32 + (lane >> 4) * 8];
                acc[nt] = __builtin_amdgcn_mfma_f32_16x16x32_bf16(af, bv, acc[nt], 0, 0, 0);
            }
        }
        __syncthreads();
    }

    // beta: reduce partials across the 4 k-quarter lanes, softmax3
    bs0 += __shfl_xor(bs0, 1); bs0 += __shfl_xor(bs0, 2);
    bs1 += __shfl_xor(bs1, 1); bs1 += __shfl_xor(bs1, 2);
    bs2 += __shfl_xor(bs2, 1); bs2 += __shfl_xor(bs2, 2);
    if (bq == 0 && rowok) {
        float s0 = bs0 + bc[0], s1 = bs1 + bc[1], s2 = bs2 + bc[2];
        float mx = fmaxf(s0, fmaxf(s1, s2));
        float e0 = __expf(s0 - mx), e1 = __expf(s1 - mx), e2 = __expf(s2 - mx);
        float inv = 1.f / (e0 + e1 + e2);
        int n = row0 + br;
        beta[n * 3 + 0] = e0 * inv;
        beta[n * 3 + 1] = e1 * inv;
        beta[n * 3 + 2] = e2 * inv;
    }

    // epilogue: bias add, convert bf16, stage to LDS, coalesced store
    #pragma unroll
    for (int nt = 0; nt < 8; ++nt) {
        int col = nt * 16 + (lane & 15);
        float bias = bl[col];
        int rbase = wv * 16 + (lane >> 4) * 4;
        #pragma unroll
        for (int r = 0; r < 4; ++r) {
            hs[rbase + r][col] = f2bf(acc[nt][r] + bias);
        }
    }
    __syncthreads();
    // 64 rows x 128 ushorts = 1024 uint4 segments: rw = c>>4 (0..63), seg = c&15
    #pragma unroll
    for (int j = 0; j < 4; ++j) {
        int c = t + 256 * j;
        int rw = c >> 4, seg = c & 15;
        if (row0 + rw < NN) {
            uint4 v = *(const uint4*)&hs[rw][seg * 8];
            *(uint4*)(hb + (size_t)(row0 + rw) * DD + seg * 8) = v;
        }
    }
}

// ---------------- al/ar attention dots per node (bf16 h) ----------------
__global__ __launch_bounds__(256) void alr_kernel(const ushort* __restrict__ hb,
                                                  const float* __restrict__ attn_l,
                                                  const float* __restrict__ attn_r,
                                                  float* __restrict__ AL,
                                                  float* __restrict__ AR) {
    int wid = threadIdx.x >> 6, lane = threadIdx.x & 63;
    int n = blockIdx.x * 4 + wid;
    uint hv = ((const uint*)hb)[(size_t)n * 64 + lane];
    float hx = bf2f((ushort)(hv & 0xffff)), hy = bf2f((ushort)(hv >> 16));
    int hd = lane >> 4;
    int cg = lane & 15;
    #pragma unroll
    for (int m = 0; m < 2; ++m) {
        float2 wl = ((const float2*)attn_l)[m * 64 + hd * 16 + cg];
        float2 wr = ((const float2*)attn_r)[m * 64 + hd * 16 + cg];
        float sl = hx * wl.x + hy * wl.y;
        float sr = hx * wr.x + hy * wr.y;
        for (int off = 1; off < 16; off <<= 1) {
            sl += __shfl_xor(sl, off);
            sr += __shfl_xor(sr, off);
        }
        if (cg == 0) {
            AL[(size_t)(m * NN + n) * 4 + hd] = sl;
            AR[(size_t)(m * NN + n) * 4 + hd] = sr;
        }
    }
}

// ---------------- CSR build ----------------
__global__ void count_kernel(const int* __restrict__ ei0, const int* __restrict__ ei1,
                             int* __restrict__ deg) {
    int e = blockIdx.x * 256 + threadIdx.x;
    if (e < EE) {
        atomicAdd(&deg[ei0[e]], 1);
    } else if (e < 2 * EE) {
        atomicAdd(&deg[NN + ei1[e - EE]], 1);
    }
}

__global__ __launch_bounds__(256) void scan1(const int* __restrict__ deg, int* __restrict__ rp,
                                             int* __restrict__ bsum, int L) {
    __shared__ int sm[256];
    int t = threadIdx.x;
    int i = blockIdx.x * 256 + t;
    int v = (i < L) ? deg[i] : 0;
    sm[t] = v;
    __syncthreads();
    for (int off = 1; off < 256; off <<= 1) {
        int o = (t >= off) ? sm[t - off] : 0;
        __syncthreads();
        sm[t] += o;
        __syncthreads();
    }
    if (i < L) rp[i] = sm[t] - v;
    if (t == 255) bsum[blockIdx.x] = sm[255];
}

__global__ __launch_bounds__(256) void scan2(int* __restrict__ bsum, int nb) {
    __shared__ int sm[256];
    int t = threadIdx.x;
    int carry = 0;
    for (int base = 0; base < nb; base += 256) {
        int i = base + t;
        int v = (i < nb) ? bsum[i] : 0;
        __syncthreads();
        sm[t] = v;
        __syncthreads();
        for (int off = 1; off < 256; off <<= 1) {
            int o = (t >= off) ? sm[t - off] : 0;
            __syncthreads();
            sm[t] += o;
            __syncthreads();
        }
        int incl = sm[t];
        int tot = sm[255];
        if (i < nb) bsum[i] = carry + incl - v;
        carry += tot;
    }
}

__global__ void scan3(int* __restrict__ rp, const int* __restrict__ bsum, int L) {
    int i = blockIdx.x * 256 + threadIdx.x;
    if (i < L) rp[i] += bsum[blockIdx.x];
    if (i == 0) rp[L] = 2 * EE;
}

__global__ void scatter_kernel(const int* __restrict__ ei0, const int* __restrict__ ei1,
                               const int* __restrict__ rp, int* __restrict__ cursor,
                               int* __restrict__ srcs) {
    int e = blockIdx.x * 256 + threadIdx.x;
    int idx, src;
    if (e < EE) {
        idx = ei0[e];
        src = ei0[EE + e];
    } else if (e < 2 * EE) {
        int e1 = e - EE;
        idx = NN + ei1[e1];
        src = ei1[EE + e1];
    } else {
        return;
    }
    int pos = rp[idx] + atomicAdd(&cursor[idx], 1);
    srcs[pos] = src;
}

// ---------------- main: per-dst softmax-aggregate + combine (bf16 h, 4-deep MLP) ----------------
__global__ __launch_bounds__(256) void main_kernel(const ushort* __restrict__ hb,
                                                   const float* __restrict__ AL,
                                                   const float* __restrict__ AR,
                                                   const float* __restrict__ beta,
                                                   const float* __restrict__ alpha_act,
                                                   const int* __restrict__ rp,
                                                   const int* __restrict__ srcs,
                                                   float* __restrict__ out) {
    int wid = threadIdx.x >> 6, lane = threadIdx.x & 63;
    int n = blockIdx.x * 4 + wid;
    const uint* h2 = (const uint*)hb;
    uint hv = h2[(size_t)n * 64 + lane];
    float hx = bf2f((ushort)(hv & 0xffff)), hy = bf2f((ushort)(hv >> 16));
    int hd = lane >> 4;
    float b0 = beta[n * 3 + 0], b1 = beta[n * 3 + 1], b2 = beta[n * 3 + 2];
    float ox = b2 * hx, oy = b2 * hy;
    float bm[2] = {b0, b1};
    #pragma unroll
    for (int m = 0; m < 2; ++m) {
        float alv = AL[(size_t)(m * NN + n) * 4 + hd];
        float am = alpha_act[m];
        int e0 = rp[m * NN + n];
        int e1 = rp[m * NN + n + 1];
        float denom = 0.f, ax = 0.f, ay = 0.f;
        int e = e0;
        for (; e + 4 <= e1; e += 4) {
            int s0 = srcs[e + 0], s1 = srcs[e + 1], s2 = srcs[e + 2], s3 = srcs[e + 3];
            float r0 = AR[(size_t)(m * NN + s0) * 4 + hd];
            float r1 = AR[(size_t)(m * NN + s1) * 4 + hd];
            float r2 = AR[(size_t)(m * NN + s2) * 4 + hd];
            float r3 = AR[(size_t)(m * NN + s3) * 4 + hd];
            uint g0 = h2[(size_t)s0 * 64 + lane];
            uint g1 = h2[(size_t)s1 * 64 + lane];
            uint g2 = h2[(size_t)s2 * 64 + lane];
            uint g3 = h2[(size_t)s3 * 64 + lane];
            float p0 = __expf((r0 + alv) * am);
            float p1 = __expf((r1 + alv) * am);
            float p2 = __expf((r2 + alv) * am);
            float p3 = __expf((r3 + alv) * am);
            denom += (p0 + p1) + (p2 + p3);
            ax += p0 * bf2f((ushort)(g0 & 0xffff)) + p1 * bf2f((ushort)(g1 & 0xffff))
                + p2 * bf2f((ushort)(g2 & 0xffff)) + p3 * bf2f((ushort)(g3 & 0xffff));
            ay += p0 * bf2f((ushort)(g0 >> 16)) + p1 * bf2f((ushort)(g1 >> 16))
                + p2 * bf2f((ushort)(g2 >> 16)) + p3 * bf2f((ushort)(g3 >> 16));
        }
        for (; e < e1; ++e) {
            int s = srcs[e];
            float rv = AR[(size_t)(m * NN + s) * 4 + hd];
            float p = __expf((rv + alv) * am);
            denom += p;
            uint g = h2[(size_t)s * 64 + lane];
            ax += p * bf2f((ushort)(g & 0xffff));
            ay += p * bf2f((ushort)(g >> 16));
        }
        float invd = (denom > 0.f) ? (1.f / denom) : 0.f;
        ox += bm[m] * ax * invd;
        oy += bm[m] * ay * invd;
    }
    float2 res;
    res.x = fmaxf(ox, 0.f);
    res.y = fmaxf(oy, 0.f);
    ((float2*)out)[(size_t)n * 64 + lane] = res;
}

// ---------------- launch ----------------
extern "C" void kernel_launch(void* const* d_in, const int* in_sizes, int n_in,
                              void* d_out, int out_size, void* d_ws, size_t ws_size,
                              hipStream_t stream) {
    const float* x      = (const float*)d_in[0];
    const int*   ei0    = (const int*)d_in[1];
    const int*   ei1    = (const int*)d_in[2];
    const float* W_lin  = (const float*)d_in[3];
    const float* b_lin  = (const float*)d_in[4];
    const float* attn_l = (const float*)d_in[5];
    const float* attn_r = (const float*)d_in[6];
    const float* alpha  = (const float*)d_in[7];
    const float* W_conv = (const float*)d_in[8];
    const float* b_conv = (const float*)d_in[9];
    float* out = (float*)d_out;

    char* ws = (char*)d_ws;
    size_t off = 0;
    ushort* hb   = (ushort*)(ws + off); off += (size_t)NN * DD * 2;        // 25.6 MB
    ushort* Wt   = (ushort*)(ws + off); off += (size_t)DD * FF * 2;        // 64 KB
    float* AL    = (float*)(ws + off);  off += (size_t)2 * NN * 4 * 4;     // 3.2 MB
    float* AR    = (float*)(ws + off);  off += (size_t)2 * NN * 4 * 4;     // 3.2 MB
    float* beta  = (float*)(ws + off);  off += (size_t)NN * 3 * 4;         // 1.2 MB
    int*   deg   = (int*)(ws + off);    off += (size_t)2 * NN * 4;
    int*   cursor= (int*)(ws + off);    off += (size_t)2 * NN * 4;
    int*   rp    = (int*)(ws + off);    off += ((size_t)2 * NN + 4) * 4;
    int*   bsum  = (int*)(ws + off);    off += 1024 * 4;
    int*   srcs  = (int*)(ws + off);    off += (size_t)2 * EE * 4;         // 8 MB

    hipMemsetAsync(deg, 0, (size_t)4 * NN * 4, stream);

    pack_w<<<DD * FF / 256, 256, 0, stream>>>(W_lin, Wt);
    fused_h<<<(NN + 63) / 64, 256, 0, stream>>>(x, Wt, b_lin, W_conv, b_conv, hb, beta);
    alr_kernel<<<NN / 4, 256, 0, stream>>>(hb, attn_l, attn_r, AL, AR);
    count_kernel<<<(2 * EE + 255) / 256, 256, 0, stream>>>(ei0, ei1, deg);
    int L = 2 * NN;
    int nb = (L + 255) / 256;
    scan1<<<nb, 256, 0, stream>>>(deg, rp, bsum, L);
    scan2<<<1, 256, 0, stream>>>(bsum, nb);
    scan3<<<nb, 256, 0, stream>>>(rp, bsum, L);
    scatter_kernel<<<(2 * EE + 255) / 256, 256, 0, stream>>>(ei0, ei1, rp, cursor, srcs);
    main_kernel<<<NN / 4, 256, 0, stream>>>(hb, AL, AR, beta, alpha, rp, srcs, out);
}

// Round 4
// 354.806 us; speedup vs baseline: 1.6115x; 1.0869x over previous
//
#include <hip/hip_runtime.h>
#include <hip/hip_bf16.h>

#define NN 100000
#define FF 256
#define DD 128
#define EE 1000000
#define NPX (NN / 8)           // 12500 nodes per XCD slice
#define PART_BLOCKS 1024
#define PART_CHUNK ((2 * EE) / (PART_BLOCKS / 8))  // 15625 edges per block

typedef __attribute__((ext_vector_type(4))) float f32x4;
typedef __attribute__((ext_vector_type(8))) short bf16x8;

__device__ __forceinline__ ushort f2bf(float f) {
    __hip_bfloat16 h = __float2bfloat16(f);
    return *reinterpret_cast<ushort*>(&h);
}
__device__ __forceinline__ float bf2f(ushort u) {
    return __uint_as_float(((uint)u) << 16);
}

// ---------------- pack W_lin (fp32 [256][128]) -> Wt (bf16 [128][256]) ----------------
__global__ void pack_w(const float* __restrict__ Wl, ushort* __restrict__ Wt) {
    int id = blockIdx.x * 256 + threadIdx.x;  // 32768 total
    int k = id >> 7, n = id & 127;
    Wt[n * FF + k] = f2bf(Wl[id]);
}

// ---------------- fused: h = x@W+b (bf16 MFMA), beta = softmax(x@Wc^T+bc) ----------------
__global__ __launch_bounds__(256) void fused_h(const float* __restrict__ x,
                                               const ushort* __restrict__ Wt,
                                               const float* __restrict__ bl,
                                               const float* __restrict__ Wc,
                                               const float* __restrict__ bc,
                                               ushort* __restrict__ hb,
                                               float* __restrict__ beta) {
    __shared__ ushort xs[64][72];    // 64 rows x BK=64 bf16, pad 8
    __shared__ ushort wsT[128][72];  // 128 cols x BK=64 bf16 (W transposed), pad 8
    __shared__ ushort hs[64][136];   // epilogue staging: 64 rows x 128, pad 8
    __shared__ float wcs[768];       // W_conv 3x256

    int t = threadIdx.x;
    int wv = t >> 6, lane = t & 63;
    int row0 = blockIdx.x * 64;
    int br = t >> 2, bq = t & 3;     // staging/beta: row br, k-quarter bq
    bool rowok = (row0 + br) < NN;

    if (t < 192) ((float4*)wcs)[t] = ((const float4*)Wc)[t];
    __syncthreads();

    f32x4 acc[8];
    #pragma unroll
    for (int i = 0; i < 8; ++i) acc[i] = (f32x4){0.f, 0.f, 0.f, 0.f};

    float bs0 = 0.f, bs1 = 0.f, bs2 = 0.f;

    for (int k0 = 0; k0 < FF; k0 += 64) {
        if (rowok) {
            const float4* xp = (const float4*)(x + (size_t)(row0 + br) * FF + k0 + bq * 16);
            #pragma unroll
            for (int j = 0; j < 4; ++j) {
                float4 v = xp[j];
                int kk = bq * 16 + j * 4;
                const float* w0 = wcs + k0 + kk;
                bs0 += v.x * w0[0] + v.y * w0[1] + v.z * w0[2] + v.w * w0[3];
                const float* w1 = wcs + 256 + k0 + kk;
                bs1 += v.x * w1[0] + v.y * w1[1] + v.z * w1[2] + v.w * w1[3];
                const float* w2 = wcs + 512 + k0 + kk;
                bs2 += v.x * w2[0] + v.y * w2[1] + v.z * w2[2] + v.w * w2[3];
                ushort4 p;
                p.x = f2bf(v.x); p.y = f2bf(v.y); p.z = f2bf(v.z); p.w = f2bf(v.w);
                *(ushort4*)&xs[br][kk] = p;
            }
        } else {
            ushort4 z = {0, 0, 0, 0};
            #pragma unroll
            for (int j = 0; j < 4; ++j) *(ushort4*)&xs[br][bq * 16 + j * 4] = z;
        }
        #pragma unroll
        for (int j = 0; j < 4; ++j) {
            int c = t + 256 * j;
            int rw = c >> 3, seg = c & 7;   // 128 rows x 8 segs
            uint4 v = *(const uint4*)(Wt + rw * FF + k0 + seg * 8);
            *(uint4*)&wsT[rw][seg * 8] = v;
        }
        __syncthreads();
        #pragma unroll
        for (int ks = 0; ks < 2; ++ks) {
            bf16x8 af = *(const bf16x8*)&xs[wv * 16 + (lane & 15)][ks * 32 + (lane >> 4) * 8];
            #pragma unroll
            for (int nt = 0; nt < 8; ++nt) {
                bf16x8 bv = *(const bf16x8*)&wsT[nt * 16 + (lane & 15)][ks * 32 + (lane >> 4) * 8];
                acc[nt] = __builtin_amdgcn_mfma_f32_16x16x32_bf16(af, bv, acc[nt], 0, 0, 0);
            }
        }
        __syncthreads();
    }

    bs0 += __shfl_xor(bs0, 1); bs0 += __shfl_xor(bs0, 2);
    bs1 += __shfl_xor(bs1, 1); bs1 += __shfl_xor(bs1, 2);
    bs2 += __shfl_xor(bs2, 1); bs2 += __shfl_xor(bs2, 2);
    if (bq == 0 && rowok) {
        float s0 = bs0 + bc[0], s1 = bs1 + bc[1], s2 = bs2 + bc[2];
        float mx = fmaxf(s0, fmaxf(s1, s2));
        float e0 = __expf(s0 - mx), e1 = __expf(s1 - mx), e2 = __expf(s2 - mx);
        float inv = 1.f / (e0 + e1 + e2);
        int n = row0 + br;
        beta[n * 3 + 0] = e0 * inv;
        beta[n * 3 + 1] = e1 * inv;
        beta[n * 3 + 2] = e2 * inv;
    }

    #pragma unroll
    for (int nt = 0; nt < 8; ++nt) {
        int col = nt * 16 + (lane & 15);
        float bias = bl[col];
        int rbase = wv * 16 + (lane >> 4) * 4;
        #pragma unroll
        for (int r = 0; r < 4; ++r) {
            hs[rbase + r][col] = f2bf(acc[nt][r] + bias);
        }
    }
    __syncthreads();
    #pragma unroll
    for (int j = 0; j < 4; ++j) {
        int c = t + 256 * j;
        int rw = c >> 4, seg = c & 15;   // 64 rows x 16 segs
        if (row0 + rw < NN) {
            uint4 v = *(const uint4*)&hs[rw][seg * 8];
            *(uint4*)(hb + (size_t)(row0 + rw) * DD + seg * 8) = v;
        }
    }
}

// ---------------- al/ar attention dots per node (bf16 h) ----------------
__global__ __launch_bounds__(256) void alr_kernel(const ushort* __restrict__ hb,
                                                  const float* __restrict__ attn_l,
                                                  const float* __restrict__ attn_r,
                                                  float* __restrict__ AL,
                                                  float* __restrict__ AR) {
    int wid = threadIdx.x >> 6, lane = threadIdx.x & 63;
    int n = blockIdx.x * 4 + wid;
    uint hv = ((const uint*)hb)[(size_t)n * 64 + lane];
    float hx = bf2f((ushort)(hv & 0xffff)), hy = bf2f((ushort)(hv >> 16));
    int hd = lane >> 4;
    int cg = lane & 15;
    #pragma unroll
    for (int m = 0; m < 2; ++m) {
        float2 wl = ((const float2*)attn_l)[m * 64 + hd * 16 + cg];
        float2 wr = ((const float2*)attn_r)[m * 64 + hd * 16 + cg];
        float sl = hx * wl.x + hy * wl.y;
        float sr = hx * wr.x + hy * wr.y;
        for (int off = 1; off < 16; off <<= 1) {
            sl += __shfl_xor(sl, off);
            sr += __shfl_xor(sr, off);
        }
        if (cg == 0) {
            AL[(size_t)(m * NN + n) * 4 + hd] = sl;
            AR[(size_t)(m * NN + n) * 4 + hd] = sr;
        }
    }
}

// ---------------- CSR build: XCD-partitioned count + scatter ----------------
// blockIdx & 7 selects the XCD slice (round-robin dispatch); each block scans a
// 1/128 chunk of all edges and only processes dsts in its slice -> all atomic
// and scatter traffic stays in the local XCD's L2 (no cross-XCD line bounce).
__global__ __launch_bounds__(256) void count_kernel(const int* __restrict__ ei0,
                                                    const int* __restrict__ ei1,
                                                    int* __restrict__ deg) {
    int b = blockIdx.x;
    int lo = (b & 7) * NPX, hi = lo + NPX;
    int e0 = (b >> 3) * PART_CHUNK;
    for (int i = threadIdx.x; i < PART_CHUNK; i += 256) {
        int e = e0 + i;
        int dst, base;
        if (e < EE) { dst = ei0[e]; base = 0; }
        else        { dst = ei1[e - EE]; base = NN; }
        if (dst >= lo && dst < hi) atomicAdd(&deg[base + dst], 1);
    }
}

__global__ __launch_bounds__(256) void scatter_kernel(const int* __restrict__ ei0,
                                                      const int* __restrict__ ei1,
                                                      const int* __restrict__ rp,
                                                      int* __restrict__ cursor,
                                                      int* __restrict__ srcs) {
    int b = blockIdx.x;
    int lo = (b & 7) * NPX, hi = lo + NPX;
    int e0 = (b >> 3) * PART_CHUNK;
    for (int i = threadIdx.x; i < PART_CHUNK; i += 256) {
        int e = e0 + i;
        int dst, src, base;
        if (e < EE) { dst = ei0[e]; src = ei0[EE + e]; base = 0; }
        else        { int ee = e - EE; dst = ei1[ee]; src = ei1[EE + ee]; base = NN; }
        if (dst >= lo && dst < hi) {
            int idx = base + dst;
            int pos = rp[idx] + atomicAdd(&cursor[idx], 1);
            srcs[pos] = src;
        }
    }
}

// ---------------- scans ----------------
__global__ __launch_bounds__(256) void scan1(const int* __restrict__ deg, int* __restrict__ rp,
                                             int* __restrict__ bsum, int L) {
    __shared__ int sm[256];
    int t = threadIdx.x;
    int i = blockIdx.x * 256 + t;
    int v = (i < L) ? deg[i] : 0;
    sm[t] = v;
    __syncthreads();
    for (int off = 1; off < 256; off <<= 1) {
        int o = (t >= off) ? sm[t - off] : 0;
        __syncthreads();
        sm[t] += o;
        __syncthreads();
    }
    if (i < L) rp[i] = sm[t] - v;
    if (t == 255) bsum[blockIdx.x] = sm[255];
}

__global__ __launch_bounds__(256) void scan2(int* __restrict__ bsum, int nb) {
    __shared__ int sm[256];
    int t = threadIdx.x;
    int carry = 0;
    for (int base = 0; base < nb; base += 256) {
        int i = base + t;
        int v = (i < nb) ? bsum[i] : 0;
        __syncthreads();
        sm[t] = v;
        __syncthreads();
        for (int off = 1; off < 256; off <<= 1) {
            int o = (t >= off) ? sm[t - off] : 0;
            __syncthreads();
            sm[t] += o;
            __syncthreads();
        }
        int incl = sm[t];
        int tot = sm[255];
        if (i < nb) bsum[i] = carry + incl - v;
        carry += tot;
    }
}

__global__ void scan3(int* __restrict__ rp, const int* __restrict__ bsum, int L) {
    int i = blockIdx.x * 256 + threadIdx.x;
    if (i < L) rp[i] += bsum[blockIdx.x];
    if (i == 0) rp[L] = 2 * EE;
}

// ---------------- main: one wave per (dst, relation), LDS combine ----------------
__global__ __launch_bounds__(256) void main_kernel(const ushort* __restrict__ hb,
                                                   const float* __restrict__ AL,
                                                   const float* __restrict__ AR,
                                                   const float* __restrict__ beta,
                                                   const float* __restrict__ alpha_act,
                                                   const int* __restrict__ rp,
                                                   const int* __restrict__ srcs,
                                                   float* __restrict__ out) {
    __shared__ float2 contribs[2][64];   // [dst slot][lane] relation-1 contribution
    int w = threadIdx.x >> 6, lane = threadIdx.x & 63;
    int slot = w >> 1, m = w & 1;
    int n = blockIdx.x * 2 + slot;
    const uint* h2 = (const uint*)hb;
    int hd = lane >> 4;

    float alv = AL[(size_t)(m * NN + n) * 4 + hd];
    float am = alpha_act[m];
    float bm = beta[n * 3 + m];
    int e0 = rp[m * NN + n];
    int e1 = rp[m * NN + n + 1];
    const float* ARm = AR + (size_t)m * NN * 4;

    float denom = 0.f, ax = 0.f, ay = 0.f;
    for (int e = e0; e < e1; e += 4) {
        int last = e1 - 1;
        int i1 = min(e + 1, last), i2 = min(e + 2, last), i3 = min(e + 3, last);
        int s0 = srcs[e], s1 = srcs[i1], s2 = srcs[i2], s3 = srcs[i3];
        float r0 = ARm[s0 * 4 + hd];
        float r1 = ARm[s1 * 4 + hd];
        float r2 = ARm[s2 * 4 + hd];
        float r3 = ARm[s3 * 4 + hd];
        uint g0 = h2[(size_t)s0 * 64 + lane];
        uint g1 = h2[(size_t)s1 * 64 + lane];
        uint g2 = h2[(size_t)s2 * 64 + lane];
        uint g3 = h2[(size_t)s3 * 64 + lane];
        float v1 = (e + 1 < e1) ? 1.f : 0.f;
        float v2 = (e + 2 < e1) ? 1.f : 0.f;
        float v3 = (e + 3 < e1) ? 1.f : 0.f;
        float p0 = __expf((r0 + alv) * am);
        float p1 = v1 * __expf((r1 + alv) * am);
        float p2 = v2 * __expf((r2 + alv) * am);
        float p3 = v3 * __expf((r3 + alv) * am);
        denom += (p0 + p1) + (p2 + p3);
        ax += p0 * bf2f((ushort)(g0 & 0xffff)) + p1 * bf2f((ushort)(g1 & 0xffff))
            + p2 * bf2f((ushort)(g2 & 0xffff)) + p3 * bf2f((ushort)(g3 & 0xffff));
        ay += p0 * bf2f((ushort)(g0 >> 16)) + p1 * bf2f((ushort)(g1 >> 16))
            + p2 * bf2f((ushort)(g2 >> 16)) + p3 * bf2f((ushort)(g3 >> 16));
    }
    float invd = (denom > 0.f) ? (1.f / denom) : 0.f;
    float cx = bm * ax * invd;
    float cy = bm * ay * invd;

    if (m == 1) contribs[slot][lane] = make_float2(cx, cy);
    __syncthreads();
    if (m == 0) {
        uint hv = h2[(size_t)n * 64 + lane];
        float b2 = beta[n * 3 + 2];
        float2 c1 = contribs[slot][lane];
        float ox = b2 * bf2f((ushort)(hv & 0xffff)) + cx + c1.x;
        float oy = b2 * bf2f((ushort)(hv >> 16)) + cy + c1.y;
        float2 res;
        res.x = fmaxf(ox, 0.f);
        res.y = fmaxf(oy, 0.f);
        ((float2*)out)[(size_t)n * 64 + lane] = res;
    }
}

// ---------------- launch ----------------
extern "C" void kernel_launch(void* const* d_in, const int* in_sizes, int n_in,
                              void* d_out, int out_size, void* d_ws, size_t ws_size,
                              hipStream_t stream) {
    const float* x      = (const float*)d_in[0];
    const int*   ei0    = (const int*)d_in[1];
    const int*   ei1    = (const int*)d_in[2];
    const float* W_lin  = (const float*)d_in[3];
    const float* b_lin  = (const float*)d_in[4];
    const float* attn_l = (const float*)d_in[5];
    const float* attn_r = (const float*)d_in[6];
    const float* alpha  = (const float*)d_in[7];
    const float* W_conv = (const float*)d_in[8];
    const float* b_conv = (const float*)d_in[9];
    float* out = (float*)d_out;

    char* ws = (char*)d_ws;
    size_t off = 0;
    ushort* hb   = (ushort*)(ws + off); off += (size_t)NN * DD * 2;        // 25.6 MB
    ushort* Wt   = (ushort*)(ws + off); off += (size_t)DD * FF * 2;        // 64 KB
    float* AL    = (float*)(ws + off);  off += (size_t)2 * NN * 4 * 4;     // 3.2 MB
    float* AR    = (float*)(ws + off);  off += (size_t)2 * NN * 4 * 4;     // 3.2 MB
    float* beta  = (float*)(ws + off);  off += (size_t)NN * 3 * 4;         // 1.2 MB
    int*   deg   = (int*)(ws + off);    off += (size_t)2 * NN * 4;
    int*   cursor= (int*)(ws + off);    off += (size_t)2 * NN * 4;
    int*   rp    = (int*)(ws + off);    off += ((size_t)2 * NN + 4) * 4;
    int*   bsum  = (int*)(ws + off);    off += 1024 * 4;
    int*   srcs  = (int*)(ws + off);    off += (size_t)2 * EE * 4;         // 8 MB

    hipMemsetAsync(deg, 0, (size_t)4 * NN * 4, stream);

    pack_w<<<DD * FF / 256, 256, 0, stream>>>(W_lin, Wt);
    fused_h<<<(NN + 63) / 64, 256, 0, stream>>>(x, Wt, b_lin, W_conv, b_conv, hb, beta);
    alr_kernel<<<NN / 4, 256, 0, stream>>>(hb, attn_l, attn_r, AL, AR);
    count_kernel<<<PART_BLOCKS, 256, 0, stream>>>(ei0, ei1, deg);
    int L = 2 * NN;
    int nb = (L + 255) / 256;
    scan1<<<nb, 256, 0, stream>>>(deg, rp, bsum, L);
    scan2<<<1, 256, 0, stream>>>(bsum, nb);
    scan3<<<nb, 256, 0, stream>>>(rp, bsum, L);
    scatter_kernel<<<PART_BLOCKS, 256, 0, stream>>>(ei0, ei1, rp, cursor, srcs);
    main_kernel<<<NN / 2, 256, 0, stream>>>(hb, AL, AR, beta, alpha, rp, srcs, out);
}